// Round 1
// baseline (434.712 us; speedup 1.0000x reference)
//
#include <hip/hip_runtime.h>

// GAT layer, N=6144, IN_F=256, OUT_F=64, HEADS=4.
// Outputs: out [6144,256] f32 then attn [4,6144,6144] f32 (concatenated in d_out).
//
// Design:
//  K0 k_prep : split x and W^T into bf16 hi/lo pairs (double-bf16 GEMM inputs).
//  K1 k_h    : h = x@W via 3x MFMA (hi*hi + lo*hi + hi*lo) -> h_t bf16 [head][o][n];
//              fused attn_src/attn_dst reductions -> srcL/dstL (pre-scaled by log2 e).
//  K2 k_maxd : per-head global max of dstL (leaky is monotone -> analytic softmax max bound
//              m_i = leaky(src_i + max_all_j dst_j), so no per-row max pass over adj).
//  K3 k_attn : per (head, 32-row tile) block, 4 waves each own a j-quarter.
//              Phase 1: row sums s_i = sum_j adj * exp2(leaky(srcL+dstL) - mL).
//              Phase 2: attn = exp2(leaky(srcL+dstL) + (log2(1/s) - mL)), nontemporal f32
//              stores (keep adj in L3), bf16 A-frag + h_t B-frag -> MFMA PV accumulation.
//              Epilogue: combine 4 waves' C-frags in LDS -> out.

#define NNODE 6144
#define INFEAT 256
#define OUTF 64
#define NHEAD 4
#define L2E 1.4426950408889634f

typedef short bf16x8 __attribute__((ext_vector_type(8)));
typedef float f32x4 __attribute__((ext_vector_type(4)));
typedef int   i32x4 __attribute__((ext_vector_type(4)));
typedef unsigned short u16x4 __attribute__((ext_vector_type(4)));

__device__ __forceinline__ unsigned short f2b(float f) {
  // round-to-nearest-even f32 -> bf16 (finite inputs only)
  unsigned u = __builtin_bit_cast(unsigned, f);
  unsigned r = u + 0x7FFFu + ((u >> 16) & 1u);
  return (unsigned short)(r >> 16);
}
__device__ __forceinline__ float b2f(unsigned short b) {
  unsigned u = ((unsigned)b) << 16;
  return __builtin_bit_cast(float, u);
}
__device__ __forceinline__ float leaky(float t) {
  return fmaxf(t, 0.f) + 0.2f * fminf(t, 0.f);
}

// ---------------- K0: prep (x hi/lo split, W transpose + hi/lo split) ----------------
__global__ __launch_bounds__(256) void k_prep(
    const float* __restrict__ x, const float* __restrict__ W,
    unsigned short* __restrict__ x_hi, unsigned short* __restrict__ x_lo,
    unsigned short* __restrict__ wt_hi, unsigned short* __restrict__ wt_lo) {
  const int tid = blockIdx.x * 256 + threadIdx.x;
  const int nth = gridDim.x * 256;
  for (int i = tid; i < NNODE * INFEAT; i += nth) {
    float f = x[i];
    unsigned short h = f2b(f);
    x_hi[i] = h;
    x_lo[i] = f2b(f - b2f(h));
  }
  for (int i = tid; i < NHEAD * INFEAT * OUTF; i += nth) {
    const int head = i / (INFEAT * OUTF);
    const int rem = i % (INFEAT * OUTF);
    const int k = rem / OUTF, o = rem % OUTF;
    float f = W[i];
    const int dst = (head * OUTF + o) * INFEAT + k;  // W^T: [head][o][k]
    unsigned short h = f2b(f);
    wt_hi[dst] = h;
    wt_lo[dst] = f2b(f - b2f(h));
  }
}

// ---------------- K1: h = x@W (double-bf16 MFMA) + attn_src/dst ----------------
__global__ __launch_bounds__(256) void k_h(
    const unsigned short* __restrict__ x_hi, const unsigned short* __restrict__ x_lo,
    const unsigned short* __restrict__ wt_hi, const unsigned short* __restrict__ wt_lo,
    const float* __restrict__ a_src, const float* __restrict__ a_dst,
    unsigned short* __restrict__ h_t, float* __restrict__ srcL, float* __restrict__ dstL) {
  const int n0 = blockIdx.x * 16;
  const int head = threadIdx.x >> 6;  // wave = head
  const int lane = threadIdx.x & 63;
  const int q = lane >> 4, l15 = lane & 15;

  f32x4 acc[4];
#pragma unroll
  for (int nt = 0; nt < 4; ++nt)
#pragma unroll
    for (int e = 0; e < 4; ++e) acc[nt][e] = 0.f;

  const unsigned short* xh = x_hi + (size_t)(n0 + l15) * INFEAT + q * 8;
  const unsigned short* xl = x_lo + (size_t)(n0 + l15) * INFEAT + q * 8;

#pragma unroll
  for (int ks = 0; ks < INFEAT / 32; ++ks) {
    bf16x8 ah = *(const bf16x8*)(xh + ks * 32);
    bf16x8 al = *(const bf16x8*)(xl + ks * 32);
#pragma unroll
    for (int nt = 0; nt < 4; ++nt) {
      const size_t boff = (size_t)(head * OUTF + nt * 16 + l15) * INFEAT + ks * 32 + q * 8;
      bf16x8 bh = *(const bf16x8*)(wt_hi + boff);
      bf16x8 bl = *(const bf16x8*)(wt_lo + boff);
      acc[nt] = __builtin_amdgcn_mfma_f32_16x16x32_bf16(ah, bh, acc[nt], 0, 0, 0);
      acc[nt] = __builtin_amdgcn_mfma_f32_16x16x32_bf16(al, bh, acc[nt], 0, 0, 0);
      acc[nt] = __builtin_amdgcn_mfma_f32_16x16x32_bf16(ah, bl, acc[nt], 0, 0, 0);
    }
  }

  // C/D layout (verified, m89): col = lane&15, row = (lane>>4)*4 + reg
  float ps[4] = {0.f, 0.f, 0.f, 0.f}, pd[4] = {0.f, 0.f, 0.f, 0.f};
#pragma unroll
  for (int nt = 0; nt < 4; ++nt) {
    const int o = nt * 16 + l15;
    const float av = a_src[head * OUTF + o];
    const float dv = a_dst[head * OUTF + o];
    unsigned short pk[4];
#pragma unroll
    for (int e = 0; e < 4; ++e) {
      float v = acc[nt][e];
      ps[e] += v * av;
      pd[e] += v * dv;
      pk[e] = f2b(v);
    }
    u16x4 pv = {pk[0], pk[1], pk[2], pk[3]};
    *(u16x4*)(h_t + (size_t)(head * OUTF + o) * NNODE + n0 + q * 4) = pv;
  }
  // reduce over o (cols live in lanes sharing q): xor 1,2,4,8
#pragma unroll
  for (int e = 0; e < 4; ++e) {
#pragma unroll
    for (int msk = 1; msk <= 8; msk <<= 1) {
      ps[e] += __shfl_xor(ps[e], msk);
      pd[e] += __shfl_xor(pd[e], msk);
    }
  }
  if (l15 == 0) {
    const int n = n0 + q * 4;
    f32x4 s4 = {ps[0] * L2E, ps[1] * L2E, ps[2] * L2E, ps[3] * L2E};
    f32x4 d4 = {pd[0] * L2E, pd[1] * L2E, pd[2] * L2E, pd[3] * L2E};
    *(f32x4*)(srcL + head * NNODE + n) = s4;
    *(f32x4*)(dstL + head * NNODE + n) = d4;
  }
}

// ---------------- K2: per-head global max of dstL ----------------
__global__ __launch_bounds__(256) void k_maxd(const float* __restrict__ dstL,
                                              float* __restrict__ maxdL) {
  const int head = blockIdx.x;
  const int t = threadIdx.x;
  float m = -INFINITY;
  for (int n = t; n < NNODE; n += 256) m = fmaxf(m, dstL[head * NNODE + n]);
#pragma unroll
  for (int msk = 1; msk <= 32; msk <<= 1) m = fmaxf(m, __shfl_xor(m, msk));
  __shared__ float red[4];
  if ((t & 63) == 0) red[t >> 6] = m;
  __syncthreads();
  if (t == 0) maxdL[head] = fmaxf(fmaxf(red[0], red[1]), fmaxf(red[2], red[3]));
}

// ---------------- K3: fused attn (sums -> normalized write + MFMA PV) ----------------
__global__ __launch_bounds__(256) void k_attn(
    const int* __restrict__ adj, const float* __restrict__ srcL,
    const float* __restrict__ dstL, const float* __restrict__ maxdL,
    const unsigned short* __restrict__ h_t,
    float* __restrict__ out, float* __restrict__ attn) {
  __shared__ float psum[32][4];
  __shared__ float sinvs[32];
  __shared__ float cbuf[4][32][64];

  const int bx = blockIdx.x;
  const int head = bx & 3;
  const int rt = bx >> 2;
  const int w = threadIdx.x >> 6;  // wave id = j-quarter
  const int lane = threadIdx.x & 63;
  const int q = lane >> 4, l15 = lane & 15;
  const int i0 = rt * 32;
  const int r0 = i0 + l15;
  const int r1 = r0 + 16;

  const float md = maxdL[head];
  const float sl0 = srcL[head * NNODE + r0];
  const float sl1 = srcL[head * NNODE + r1];
  const float mL0 = leaky(sl0 + md);  // analytic softmax-max bound (scaled by log2 e)
  const float mL1 = leaky(sl1 + md);
  const float* dptr = dstL + head * NNODE;
  const int jb = w * (NNODE / 4);
  const int jend = jb + (NNODE / 4);

  // -------- phase 1: row sums over this wave's j-quarter --------
  float s0 = 0.f, s1 = 0.f;
  for (int j0 = jb + q * 8; j0 < jend; j0 += 32) {
    f32x4 d0 = *(const f32x4*)(dptr + j0);
    f32x4 d1 = *(const f32x4*)(dptr + j0 + 4);
    i32x4 a00 = *(const i32x4*)(adj + (size_t)r0 * NNODE + j0);
    i32x4 a01 = *(const i32x4*)(adj + (size_t)r0 * NNODE + j0 + 4);
    i32x4 a10 = *(const i32x4*)(adj + (size_t)r1 * NNODE + j0);
    i32x4 a11 = *(const i32x4*)(adj + (size_t)r1 * NNODE + j0 + 4);
#pragma unroll
    for (int e = 0; e < 8; ++e) {
      const float de = (e < 4) ? d0[e & 3] : d1[e & 3];
      const int ae0 = (e < 4) ? a00[e & 3] : a01[e & 3];
      const int ae1 = (e < 4) ? a10[e & 3] : a11[e & 3];
      float t0 = sl0 + de;
      float lr0 = fmaxf(t0, 0.f) + 0.2f * fminf(t0, 0.f);
      s0 += ae0 ? __builtin_exp2f(lr0 - mL0) : 0.f;
      float t1 = sl1 + de;
      float lr1 = fmaxf(t1, 0.f) + 0.2f * fminf(t1, 0.f);
      s1 += ae1 ? __builtin_exp2f(lr1 - mL1) : 0.f;
    }
  }
  s0 += __shfl_xor(s0, 16); s0 += __shfl_xor(s0, 32);
  s1 += __shfl_xor(s1, 16); s1 += __shfl_xor(s1, 32);
  if (lane < 16) { psum[lane][w] = s0; psum[lane + 16][w] = s1; }
  __syncthreads();
  if (threadIdx.x < 32) {
    float t = psum[threadIdx.x][0] + psum[threadIdx.x][1] +
              psum[threadIdx.x][2] + psum[threadIdx.x][3];
    sinvs[threadIdx.x] = (t > 0.f) ? (1.f / t) : 0.f;  // empty row -> attn = 0 (nan_to_num)
  }
  __syncthreads();
  // fold normalization into the exponent: log2(0) = -inf -> exp2 -> 0
  const float cc0 = __builtin_log2f(sinvs[l15]) - mL0;
  const float cc1 = __builtin_log2f(sinvs[l15 + 16]) - mL1;

  // -------- phase 2: normalized attn write + PV MFMA --------
  f32x4 acc[2][4];
#pragma unroll
  for (int m = 0; m < 2; ++m)
#pragma unroll
    for (int nt = 0; nt < 4; ++nt)
#pragma unroll
      for (int e = 0; e < 4; ++e) acc[m][nt][e] = 0.f;

  float* attnH = attn + (size_t)head * NNODE * NNODE;
  for (int j0 = jb + q * 8; j0 < jend; j0 += 32) {
    f32x4 d0 = *(const f32x4*)(dptr + j0);
    f32x4 d1 = *(const f32x4*)(dptr + j0 + 4);
    i32x4 a00 = *(const i32x4*)(adj + (size_t)r0 * NNODE + j0);
    i32x4 a01 = *(const i32x4*)(adj + (size_t)r0 * NNODE + j0 + 4);
    i32x4 a10 = *(const i32x4*)(adj + (size_t)r1 * NNODE + j0);
    i32x4 a11 = *(const i32x4*)(adj + (size_t)r1 * NNODE + j0 + 4);
    float p0v[8], p1v[8];
#pragma unroll
    for (int e = 0; e < 8; ++e) {
      const float de = (e < 4) ? d0[e & 3] : d1[e & 3];
      const int ae0 = (e < 4) ? a00[e & 3] : a01[e & 3];
      const int ae1 = (e < 4) ? a10[e & 3] : a11[e & 3];
      float t0 = sl0 + de;
      float lr0 = fmaxf(t0, 0.f) + 0.2f * fminf(t0, 0.f);
      p0v[e] = ae0 ? __builtin_exp2f(lr0 + cc0) : 0.f;
      float t1 = sl1 + de;
      float lr1 = fmaxf(t1, 0.f) + 0.2f * fminf(t1, 0.f);
      p1v[e] = ae1 ? __builtin_exp2f(lr1 + cc1) : 0.f;
    }
    // nontemporal: 604 MB write stream must not evict adj from L3
    f32x4 q00 = {p0v[0], p0v[1], p0v[2], p0v[3]};
    f32x4 q01 = {p0v[4], p0v[5], p0v[6], p0v[7]};
    f32x4 q10 = {p1v[0], p1v[1], p1v[2], p1v[3]};
    f32x4 q11 = {p1v[4], p1v[5], p1v[6], p1v[7]};
    float* ar0 = attnH + (size_t)r0 * NNODE + j0;
    float* ar1 = attnH + (size_t)r1 * NNODE + j0;
    __builtin_nontemporal_store(q00, (f32x4*)ar0);
    __builtin_nontemporal_store(q01, (f32x4*)(ar0 + 4));
    __builtin_nontemporal_store(q10, (f32x4*)ar1);
    __builtin_nontemporal_store(q11, (f32x4*)(ar1 + 4));

    // A-frag: row = lane&15, k = (lane>>4)*8+e  (q already folded into j0)
    bf16x8 af0, af1;
#pragma unroll
    for (int e = 0; e < 8; ++e) {
      af0[e] = (short)f2b(p0v[e]);
      af1[e] = (short)f2b(p1v[e]);
    }
#pragma unroll
    for (int nt = 0; nt < 4; ++nt) {
      // B-frag from h_t[head][o][j]: col = lane&15 (o), k = (lane>>4)*8+e (j)
      bf16x8 bf = *(const bf16x8*)(h_t + (size_t)(head * OUTF + nt * 16 + l15) * NNODE + j0);
      acc[0][nt] = __builtin_amdgcn_mfma_f32_16x16x32_bf16(af0, bf, acc[0][nt], 0, 0, 0);
      acc[1][nt] = __builtin_amdgcn_mfma_f32_16x16x32_bf16(af1, bf, acc[1][nt], 0, 0, 0);
    }
  }

  // -------- epilogue: combine the 4 waves' partial C over j-quarters --------
#pragma unroll
  for (int m = 0; m < 2; ++m)
#pragma unroll
    for (int nt = 0; nt < 4; ++nt)
#pragma unroll
      for (int e = 0; e < 4; ++e)
        cbuf[w][m * 16 + q * 4 + e][nt * 16 + l15] = acc[m][nt][e];
  __syncthreads();
  {
    const int row = threadIdx.x >> 3;
    const int oc = (threadIdx.x & 7) * 8;
    float v[8];
#pragma unroll
    for (int e = 0; e < 8; ++e)
      v[e] = cbuf[0][row][oc + e] + cbuf[1][row][oc + e] +
             cbuf[2][row][oc + e] + cbuf[3][row][oc + e];
    float* op = out + (size_t)(i0 + row) * (NHEAD * OUTF) + head * OUTF + oc;
    f32x4 v0 = {v[0], v[1], v[2], v[3]};
    f32x4 v1 = {v[4], v[5], v[6], v[7]};
    *(f32x4*)op = v0;
    *(f32x4*)(op + 4) = v1;
  }
}

extern "C" void kernel_launch(void* const* d_in, const int* in_sizes, int n_in,
                              void* d_out, int out_size, void* d_ws, size_t ws_size,
                              hipStream_t stream) {
  const float* x = (const float*)d_in[0];
  const int* adj = (const int*)d_in[1];
  const float* W = (const float*)d_in[2];
  const float* a_src = (const float*)d_in[3];
  const float* a_dst = (const float*)d_in[4];

  float* out = (float*)d_out;                       // [6144][256]
  float* attn = out + (size_t)NNODE * NHEAD * OUTF; // [4][6144][6144]

  // workspace carve (~9.9 MB total)
  unsigned short* x_hi = (unsigned short*)d_ws;                 // 6144*256
  unsigned short* x_lo = x_hi + (size_t)NNODE * INFEAT;
  unsigned short* wt_hi = x_lo + (size_t)NNODE * INFEAT;        // 4*64*256 (transposed)
  unsigned short* wt_lo = wt_hi + (size_t)NHEAD * OUTF * INFEAT;
  unsigned short* h_t = wt_lo + (size_t)NHEAD * OUTF * INFEAT;  // [4][64][6144] bf16
  float* srcL = (float*)(h_t + (size_t)NHEAD * OUTF * NNODE);   // [4][6144] (x log2e)
  float* dstL = srcL + NHEAD * NNODE;                           // [4][6144] (x log2e)
  float* maxdL = dstL + NHEAD * NNODE;                          // [4]

  k_prep<<<1024, 256, 0, stream>>>(x, W, x_hi, x_lo, wt_hi, wt_lo);
  k_h<<<NNODE / 16, 256, 0, stream>>>(x_hi, x_lo, wt_hi, wt_lo, a_src, a_dst, h_t, srcL, dstL);
  k_maxd<<<NHEAD, 256, 0, stream>>>(dstL, maxdL);
  k_attn<<<(NNODE / 32) * NHEAD, 256, 0, stream>>>(adj, srcL, dstL, maxdL, h_t, out, attn);
}

// Round 2
// 275.241 us; speedup vs baseline: 1.5794x; 1.5794x over previous
//
#include <hip/hip_runtime.h>

// GAT layer, N=6144, IN_F=256, OUT_F=64, HEADS=4.
// Outputs: out [6144,256] f32 then attn [4,6144,6144] f32 (concatenated in d_out).
//
//  K0 k_prep : split x and W^T into bf16 hi/lo pairs (double-bf16 GEMM inputs).
//  K1 k_h    : h = x@W via 3x MFMA -> h_t bf16 [head][o][n]; fused attn_src/attn_dst
//              reductions -> srcL/dstL (pre-scaled by log2 e).
//  K2 k_maxd : per-head global max of dstL (leaky monotone -> analytic softmax max bound).
//  K3 k_sums : ONE adj pass, all 4 heads at once (wave per row): row sums ->
//              ccL[h][r] = -log2(s) - mL  (or -inf for empty rows).
//  K4 k_attn2: single adj pass. Per (head, 32-row tile): compute normalized p,
//              repack the wave's 32x32 tile through wave-private LDS, store attn with
//              FULL-LINE-coalesced nontemporal instructions (16 complete 64B lines per
//              instr -> no RMW amplification, no L3 allocation so adj stays resident),
//              MFMA PV accumulation, LDS-combine epilogue -> out.

#define NNODE 6144
#define INFEAT 256
#define OUTF 64
#define NHEAD 4
#define L2E 1.4426950408889634f

typedef short bf16x8 __attribute__((ext_vector_type(8)));
typedef float f32x4 __attribute__((ext_vector_type(4)));
typedef int   i32x4 __attribute__((ext_vector_type(4)));
typedef unsigned short u16x4 __attribute__((ext_vector_type(4)));

__device__ __forceinline__ unsigned short f2b(float f) {
  unsigned u = __builtin_bit_cast(unsigned, f);
  unsigned r = u + 0x7FFFu + ((u >> 16) & 1u);
  return (unsigned short)(r >> 16);
}
__device__ __forceinline__ float b2f(unsigned short b) {
  unsigned u = ((unsigned)b) << 16;
  return __builtin_bit_cast(float, u);
}
__device__ __forceinline__ float leaky(float t) {
  return fmaxf(t, 0.f) + 0.2f * fminf(t, 0.f);
}
__device__ __forceinline__ void lds_fence() {
  asm volatile("s_waitcnt lgkmcnt(0)" ::: "memory");
  __builtin_amdgcn_sched_barrier(0);
}

// ---------------- K0: prep ----------------
__global__ __launch_bounds__(256) void k_prep(
    const float* __restrict__ x, const float* __restrict__ W,
    unsigned short* __restrict__ x_hi, unsigned short* __restrict__ x_lo,
    unsigned short* __restrict__ wt_hi, unsigned short* __restrict__ wt_lo) {
  const int tid = blockIdx.x * 256 + threadIdx.x;
  const int nth = gridDim.x * 256;
  for (int i = tid; i < NNODE * INFEAT; i += nth) {
    float f = x[i];
    unsigned short h = f2b(f);
    x_hi[i] = h;
    x_lo[i] = f2b(f - b2f(h));
  }
  for (int i = tid; i < NHEAD * INFEAT * OUTF; i += nth) {
    const int head = i / (INFEAT * OUTF);
    const int rem = i % (INFEAT * OUTF);
    const int k = rem / OUTF, o = rem % OUTF;
    float f = W[i];
    const int dst = (head * OUTF + o) * INFEAT + k;
    unsigned short h = f2b(f);
    wt_hi[dst] = h;
    wt_lo[dst] = f2b(f - b2f(h));
  }
}

// ---------------- K1: h = x@W (double-bf16 MFMA) + attn_src/dst ----------------
__global__ __launch_bounds__(256) void k_h(
    const unsigned short* __restrict__ x_hi, const unsigned short* __restrict__ x_lo,
    const unsigned short* __restrict__ wt_hi, const unsigned short* __restrict__ wt_lo,
    const float* __restrict__ a_src, const float* __restrict__ a_dst,
    unsigned short* __restrict__ h_t, float* __restrict__ srcL, float* __restrict__ dstL) {
  const int n0 = blockIdx.x * 16;
  const int head = threadIdx.x >> 6;
  const int lane = threadIdx.x & 63;
  const int q = lane >> 4, l15 = lane & 15;

  f32x4 acc[4];
#pragma unroll
  for (int nt = 0; nt < 4; ++nt)
#pragma unroll
    for (int e = 0; e < 4; ++e) acc[nt][e] = 0.f;

  const unsigned short* xh = x_hi + (size_t)(n0 + l15) * INFEAT + q * 8;
  const unsigned short* xl = x_lo + (size_t)(n0 + l15) * INFEAT + q * 8;

#pragma unroll
  for (int ks = 0; ks < INFEAT / 32; ++ks) {
    bf16x8 ah = *(const bf16x8*)(xh + ks * 32);
    bf16x8 al = *(const bf16x8*)(xl + ks * 32);
#pragma unroll
    for (int nt = 0; nt < 4; ++nt) {
      const size_t boff = (size_t)(head * OUTF + nt * 16 + l15) * INFEAT + ks * 32 + q * 8;
      bf16x8 bh = *(const bf16x8*)(wt_hi + boff);
      bf16x8 bl = *(const bf16x8*)(wt_lo + boff);
      acc[nt] = __builtin_amdgcn_mfma_f32_16x16x32_bf16(ah, bh, acc[nt], 0, 0, 0);
      acc[nt] = __builtin_amdgcn_mfma_f32_16x16x32_bf16(al, bh, acc[nt], 0, 0, 0);
      acc[nt] = __builtin_amdgcn_mfma_f32_16x16x32_bf16(ah, bl, acc[nt], 0, 0, 0);
    }
  }

  float ps[4] = {0.f, 0.f, 0.f, 0.f}, pd[4] = {0.f, 0.f, 0.f, 0.f};
#pragma unroll
  for (int nt = 0; nt < 4; ++nt) {
    const int o = nt * 16 + l15;
    const float av = a_src[head * OUTF + o];
    const float dv = a_dst[head * OUTF + o];
    unsigned short pk[4];
#pragma unroll
    for (int e = 0; e < 4; ++e) {
      float v = acc[nt][e];
      ps[e] += v * av;
      pd[e] += v * dv;
      pk[e] = f2b(v);
    }
    u16x4 pv = {pk[0], pk[1], pk[2], pk[3]};
    *(u16x4*)(h_t + (size_t)(head * OUTF + o) * NNODE + n0 + q * 4) = pv;
  }
#pragma unroll
  for (int e = 0; e < 4; ++e) {
#pragma unroll
    for (int msk = 1; msk <= 8; msk <<= 1) {
      ps[e] += __shfl_xor(ps[e], msk);
      pd[e] += __shfl_xor(pd[e], msk);
    }
  }
  if (l15 == 0) {
    const int n = n0 + q * 4;
    f32x4 s4 = {ps[0] * L2E, ps[1] * L2E, ps[2] * L2E, ps[3] * L2E};
    f32x4 d4 = {pd[0] * L2E, pd[1] * L2E, pd[2] * L2E, pd[3] * L2E};
    *(f32x4*)(srcL + head * NNODE + n) = s4;
    *(f32x4*)(dstL + head * NNODE + n) = d4;
  }
}

// ---------------- K2: per-head global max of dstL ----------------
__global__ __launch_bounds__(256) void k_maxd(const float* __restrict__ dstL,
                                              float* __restrict__ maxdL) {
  const int head = blockIdx.x;
  const int t = threadIdx.x;
  float m = -INFINITY;
  for (int n = t; n < NNODE; n += 256) m = fmaxf(m, dstL[head * NNODE + n]);
#pragma unroll
  for (int msk = 1; msk <= 32; msk <<= 1) m = fmaxf(m, __shfl_xor(m, msk));
  __shared__ float red[4];
  if ((t & 63) == 0) red[t >> 6] = m;
  __syncthreads();
  if (t == 0) maxdL[head] = fmaxf(fmaxf(red[0], red[1]), fmaxf(red[2], red[3]));
}

// ---------------- K3: one adj pass, all heads: ccL[h][r] = -log2(s)-mL ----------------
__global__ __launch_bounds__(256) void k_sums(
    const int* __restrict__ adj, const float* __restrict__ srcL,
    const float* __restrict__ dstL, const float* __restrict__ maxdL,
    float* __restrict__ ccL) {
  const int r = blockIdx.x * 4 + (threadIdx.x >> 6);  // wave per row
  const int lane = threadIdx.x & 63;
  float sl[NHEAD], mL[NHEAD], s[NHEAD];
#pragma unroll
  for (int h = 0; h < NHEAD; ++h) {
    sl[h] = srcL[h * NNODE + r];
    mL[h] = leaky(sl[h] + maxdL[h]);
    s[h] = 0.f;
  }
  const int* arow = adj + (size_t)r * NNODE;
  for (int j = lane * 4; j < NNODE; j += 256) {
    i32x4 a = *(const i32x4*)(arow + j);
#pragma unroll
    for (int h = 0; h < NHEAD; ++h) {
      f32x4 d = *(const f32x4*)(dstL + h * NNODE + j);
#pragma unroll
      for (int e = 0; e < 4; ++e) {
        float t = sl[h] + d[e];
        float lr = fmaxf(t, 0.f) + 0.2f * fminf(t, 0.f);
        s[h] += a[e] ? __builtin_exp2f(lr - mL[h]) : 0.f;
      }
    }
  }
#pragma unroll
  for (int h = 0; h < NHEAD; ++h) {
#pragma unroll
    for (int msk = 1; msk <= 32; msk <<= 1) s[h] += __shfl_xor(s[h], msk);
  }
  if (lane == 0) {
#pragma unroll
    for (int h = 0; h < NHEAD; ++h)
      ccL[h * NNODE + r] = (s[h] > 0.f) ? (-__builtin_log2f(s[h]) - mL[h]) : -INFINITY;
  }
}

// ---------------- K4: single-pass attn write (full-line nt) + MFMA PV ----------------
__global__ __launch_bounds__(256) void k_attn2(
    const int* __restrict__ adj, const float* __restrict__ srcL,
    const float* __restrict__ ccL, const float* __restrict__ dstL,
    const unsigned short* __restrict__ h_t,
    float* __restrict__ out, float* __restrict__ attn) {
  // union: per-wave repack buffers (4 x 32 rows x 36 floats) | epilogue cbuf [4][32][64]
  __shared__ float smem_f[8192];  // 32 KB

  const int bx = blockIdx.x;
  const int head = bx & 3;  // 4 consecutive blocks share adj rows -> L3 reuse
  const int rt = bx >> 2;
  const int w = threadIdx.x >> 6;
  const int lane = threadIdx.x & 63;
  const int q = lane >> 4, l15 = lane & 15;
  const int i0 = rt * 32;
  const int r0 = i0 + l15;
  const int r1 = r0 + 16;

  const float sl0 = srcL[head * NNODE + r0];
  const float sl1 = srcL[head * NNODE + r1];
  const float cc0 = ccL[head * NNODE + r0];  // -log2(sum) - mL  (-inf if empty row)
  const float cc1 = ccL[head * NNODE + r1];
  const float* dptr = dstL + head * NNODE;
  float* pb = smem_f + w * 1152;  // 32 x 36 floats, wave-private

  f32x4 acc[2][4];
#pragma unroll
  for (int m = 0; m < 2; ++m)
#pragma unroll
    for (int nt = 0; nt < 4; ++nt)
#pragma unroll
      for (int e = 0; e < 4; ++e) acc[m][nt][e] = 0.f;

  float* attnH = attn + (size_t)head * NNODE * NNODE;
  const int jb = w * (NNODE / 4);
  const int jend = jb + (NNODE / 4);

  for (int jc = jb; jc < jend; jc += 32) {
    const int j0 = jc + q * 8;
    f32x4 d0 = *(const f32x4*)(dptr + j0);
    f32x4 d1 = *(const f32x4*)(dptr + j0 + 4);
    i32x4 a00 = *(const i32x4*)(adj + (size_t)r0 * NNODE + j0);
    i32x4 a01 = *(const i32x4*)(adj + (size_t)r0 * NNODE + j0 + 4);
    i32x4 a10 = *(const i32x4*)(adj + (size_t)r1 * NNODE + j0);
    i32x4 a11 = *(const i32x4*)(adj + (size_t)r1 * NNODE + j0 + 4);
    float p0v[8], p1v[8];
#pragma unroll
    for (int e = 0; e < 8; ++e) {
      const float de = (e < 4) ? d0[e & 3] : d1[e & 3];
      const int ae0 = (e < 4) ? a00[e & 3] : a01[e & 3];
      const int ae1 = (e < 4) ? a10[e & 3] : a11[e & 3];
      float t0 = sl0 + de;
      float lr0 = fmaxf(t0, 0.f) + 0.2f * fminf(t0, 0.f);
      p0v[e] = ae0 ? __builtin_exp2f(lr0 + cc0) : 0.f;
      float t1 = sl1 + de;
      float lr1 = fmaxf(t1, 0.f) + 0.2f * fminf(t1, 0.f);
      p1v[e] = ae1 ? __builtin_exp2f(lr1 + cc1) : 0.f;
    }

    // ---- repack through wave-private LDS, then full-line nt stores ----
    {
      f32x4 q00 = {p0v[0], p0v[1], p0v[2], p0v[3]};
      f32x4 q01 = {p0v[4], p0v[5], p0v[6], p0v[7]};
      f32x4 q10 = {p1v[0], p1v[1], p1v[2], p1v[3]};
      f32x4 q11 = {p1v[4], p1v[5], p1v[6], p1v[7]};
      *(f32x4*)&pb[l15 * 36 + q * 8] = q00;
      *(f32x4*)&pb[l15 * 36 + q * 8 + 4] = q01;
      *(f32x4*)&pb[(l15 + 16) * 36 + q * 8] = q10;
      *(f32x4*)&pb[(l15 + 16) * 36 + q * 8 + 4] = q11;
    }
    lds_fence();  // writes visible to all lanes of this wave
#pragma unroll
    for (int t = 0; t < 4; ++t) {
      const int rr = t * 8 + (lane >> 3);
      const int c = (lane & 7) * 4;
      f32x4 v = *(const f32x4*)&pb[rr * 36 + c];
      // 64 lanes cover 8 rows x 128B each: every 64B line fully written
      __builtin_nontemporal_store(v, (f32x4*)(attnH + (size_t)(i0 + rr) * NNODE + jc + c));
    }
    lds_fence();  // reads retired before next iteration's writes

    // ---- PV MFMA (A-frag from registers, unchanged layout) ----
    bf16x8 af0, af1;
#pragma unroll
    for (int e = 0; e < 8; ++e) {
      af0[e] = (short)f2b(p0v[e]);
      af1[e] = (short)f2b(p1v[e]);
    }
#pragma unroll
    for (int nt = 0; nt < 4; ++nt) {
      bf16x8 bf = *(const bf16x8*)(h_t + (size_t)(head * OUTF + nt * 16 + l15) * NNODE + j0);
      acc[0][nt] = __builtin_amdgcn_mfma_f32_16x16x32_bf16(af0, bf, acc[0][nt], 0, 0, 0);
      acc[1][nt] = __builtin_amdgcn_mfma_f32_16x16x32_bf16(af1, bf, acc[1][nt], 0, 0, 0);
    }
  }

  // -------- epilogue: combine the 4 waves' partial C over j-quarters --------
  __syncthreads();  // pbuf -> cbuf aliasing: all waves done with pbuf
  float (*cbuf)[32][64] = (float(*)[32][64])smem_f;
#pragma unroll
  for (int m = 0; m < 2; ++m)
#pragma unroll
    for (int nt = 0; nt < 4; ++nt)
#pragma unroll
      for (int e = 0; e < 4; ++e)
        cbuf[w][m * 16 + q * 4 + e][nt * 16 + l15] = acc[m][nt][e];
  __syncthreads();
  {
    const int row = threadIdx.x >> 3;
    const int oc = (threadIdx.x & 7) * 8;
    float v[8];
#pragma unroll
    for (int e = 0; e < 8; ++e)
      v[e] = cbuf[0][row][oc + e] + cbuf[1][row][oc + e] +
             cbuf[2][row][oc + e] + cbuf[3][row][oc + e];
    float* op = out + (size_t)(i0 + row) * (NHEAD * OUTF) + head * OUTF + oc;
    f32x4 v0 = {v[0], v[1], v[2], v[3]};
    f32x4 v1 = {v[4], v[5], v[6], v[7]};
    *(f32x4*)op = v0;
    *(f32x4*)(op + 4) = v1;
  }
}

extern "C" void kernel_launch(void* const* d_in, const int* in_sizes, int n_in,
                              void* d_out, int out_size, void* d_ws, size_t ws_size,
                              hipStream_t stream) {
  const float* x = (const float*)d_in[0];
  const int* adj = (const int*)d_in[1];
  const float* W = (const float*)d_in[2];
  const float* a_src = (const float*)d_in[3];
  const float* a_dst = (const float*)d_in[4];

  float* out = (float*)d_out;                        // [6144][256]
  float* attn = out + (size_t)NNODE * NHEAD * OUTF;  // [4][6144][6144]

  unsigned short* x_hi = (unsigned short*)d_ws;
  unsigned short* x_lo = x_hi + (size_t)NNODE * INFEAT;
  unsigned short* wt_hi = x_lo + (size_t)NNODE * INFEAT;
  unsigned short* wt_lo = wt_hi + (size_t)NHEAD * OUTF * INFEAT;
  unsigned short* h_t = wt_lo + (size_t)NHEAD * OUTF * INFEAT;  // [4][64][6144] bf16
  float* srcL = (float*)(h_t + (size_t)NHEAD * OUTF * NNODE);   // [4][6144]
  float* dstL = srcL + NHEAD * NNODE;                           // [4][6144]
  float* maxdL = dstL + NHEAD * NNODE;                          // [4]
  float* ccL = maxdL + 4;                                       // [4][6144]

  k_prep<<<1024, 256, 0, stream>>>(x, W, x_hi, x_lo, wt_hi, wt_lo);
  k_h<<<NNODE / 16, 256, 0, stream>>>(x_hi, x_lo, wt_hi, wt_lo, a_src, a_dst, h_t, srcL, dstL);
  k_maxd<<<NHEAD, 256, 0, stream>>>(dstL, maxdL);
  k_sums<<<NNODE / 4, 256, 0, stream>>>(adj, srcL, dstL, maxdL, ccL);
  k_attn2<<<(NNODE / 32) * NHEAD, 256, 0, stream>>>(adj, srcL, ccL, dstL, h_t, out, attn);
}